// Round 8
// baseline (89.795 us; speedup 1.0000x reference)
//
#include <hip/hip_runtime.h>
#include <hip/hip_bf16.h>

// Fused causal attention, S=2048 B=2 H=16 D=128, sbhd, fp32 in/out, bf16 MFMA.
// Round 8: two-kernel plan.
//  prep: K -> bf16 tile-linear (XOR-swizzle baked), V -> bf16 transposed +
//        p-permuted + swizzle baked, into d_ws (32 MB). Tiles of 16 KB per
//        (bh, kv64) so main staging is address-linear.
//  main: QBLK=128 (32 q-rows/wave, halves LDS volume/FLOP), KVBLK=64,
//        async global_load_lds staging (un-sinkable, vmcnt-counted),
//        fragment-linear conflict-free LDS reads, exp2 softmax, defer-max.

#define DDIM    128
#define ROWSTR  4096           // B*H*D element stride along s/t
#define QBLK    128
#define KVBLK   64
#define NQT     16             // 2048 / QBLK
#define QSCALE  0.1275174190023967f   // (1/sqrt(128)) * log2(e)
#define TILE_B  16384
#define VOFF    ((size_t)32 * 32 * 16384)   // 16 MiB: V region offset in ws

typedef __attribute__((ext_vector_type(4))) float f32x4;
typedef __attribute__((ext_vector_type(8))) short s16x8;

__device__ inline unsigned pk2bf(float a, float b) {
    union { __hip_bfloat162 h; unsigned u; } cv;
    cv.h = __float22bfloat162_rn(float2{a, b});
    return cv.u;
}

__device__ inline void gload_lds16(const void* g, void* l) {
    __builtin_amdgcn_global_load_lds(
        (const __attribute__((address_space(1))) unsigned int*)g,
        (__attribute__((address_space(3))) unsigned int*)l, 16, 0, 0);
}

// ---------------- pre-pass: K cvt+swizzle, V transpose+perm+swizzle ---------
// Kbf tile byte a holds K[row=a>>8][dbyte=(a&255)^((row&7)<<4)].
// Vtp tile byte a holds Vt[dd=a>>7][pbyte=(a&127)^((dd&7)<<4)], where
// p = 32hf+8g+4u+r  <->  kv = 32hf+16u+4g+r.
__global__ __launch_bounds__(256)
void prep_kernel(const float* __restrict__ k, const float* __restrict__ v,
                 char* __restrict__ ws)
{
    __shared__ unsigned short ldsT[128 * 72];
    const int bid = blockIdx.x;
    const int op  = bid >> 10;           // 0 = K, 1 = V
    const int bh  = (bid >> 5) & 31;
    const int kvt = bid & 31;
    const int tid = threadIdx.x;

    if (op == 0) {
        const int r = tid >> 2, dgrp = (tid & 3) * 32;
        const float* src = k + (size_t)(kvt * 64 + r) * ROWSTR + bh * DDIM + dgrp;
        f32x4 a[8];
#pragma unroll
        for (int i = 0; i < 8; ++i) a[i] = *(const f32x4*)(src + 4 * i);
        char* dst = ws + ((size_t)(bh * 32 + kvt)) * TILE_B + r * 256;
        const unsigned sw = (unsigned)(r & 7) << 4;
#pragma unroll
        for (int c = 0; c < 4; ++c) {
            s16x8 t; unsigned* tu = (unsigned*)&t;
            tu[0] = pk2bf(a[2 * c][0],     a[2 * c][1]);
            tu[1] = pk2bf(a[2 * c][2],     a[2 * c][3]);
            tu[2] = pk2bf(a[2 * c + 1][0], a[2 * c + 1][1]);
            tu[3] = pk2bf(a[2 * c + 1][2], a[2 * c + 1][3]);
            *(s16x8*)(dst + ((unsigned)(dgrp * 2 + 16 * c) ^ sw)) = t;
        }
    } else {
        const int c = tid >> 2, dgrp = (tid & 3) * 32;
        const float* src = v + (size_t)(kvt * 64 + c) * ROWSTR + bh * DDIM + dgrp;
#pragma unroll
        for (int i = 0; i < 8; ++i) {
            f32x4 a = *(const f32x4*)(src + 4 * i);
#pragma unroll
            for (int jj = 0; jj < 4; ++jj) {
                int d = dgrp + 4 * i + jj;
                union { float f; unsigned u; } cv; cv.f = a[jj];
                unsigned rr = cv.u + 0x7fffu + ((cv.u >> 16) & 1u);
                ldsT[d * 72 + (c ^ ((d >> 5) << 4))] = (unsigned short)(rr >> 16);
            }
        }
        __syncthreads();
        const int dd = tid >> 1, half = tid & 1;
        char* dst = ws + VOFF + ((size_t)(bh * 32 + kvt)) * TILE_B + dd * 128;
        const unsigned swd = (unsigned)(dd & 7) << 4;
        const unsigned swk = (unsigned)(dd >> 5) << 4;
#pragma unroll
        for (int c16 = 0; c16 < 4; ++c16) {
            s16x8 t; unsigned short* tp = (unsigned short*)&t;
#pragma unroll
            for (int j = 0; j < 8; ++j) {
                int kv = 32 * half + 16 * (j >> 2) + 4 * c16 + (j & 3);
                tp[j] = ldsT[dd * 72 + ((unsigned)kv ^ swk)];
            }
            *(s16x8*)(dst + ((unsigned)(64 * half + 16 * c16) ^ swd)) = t;
        }
    }
}

// ---------------- main attention kernel ------------------------------------
__global__ __launch_bounds__(256, 2)
void fattn_kernel(const float* __restrict__ q, const char* __restrict__ ws,
                  float* __restrict__ out)
{
    __shared__ char lds[2][32768];   // [buf][ K 16KB | V 16KB ]

    const int tid = threadIdx.x;
    const int w = tid >> 6, l = tid & 63, g = l >> 4, lr = l & 15;
    const int bid = blockIdx.x;
    const int bh = bid & 31;          // same-head blocks share an XCD
    const int j  = bid >> 5;          // 0..15
    // best-effort complementary pairing: qt(j)+qt(j+8) == 15
    const int qt = (j < 8) ? (15 - 2 * j) : (2 * j - 16);

    const int nt = 2 * qt + 2;
    const int qb = qt * QBLK;

    // staging source base (per-lane); V region at constant +VOFF
    const int lanoff = w * 4096 + l * 16;
    const char* gK0 = ws + (size_t)(bh * 32) * TILE_B + lanoff;

    auto stage_async = [&](int buf, int t) {
        const char* gk = gK0 + (size_t)t * TILE_B;
        const char* gv = gk + VOFF;
        char* lk = &lds[buf][0]     + w * 4096;
        char* lv = &lds[buf][16384] + w * 4096;
#pragma unroll
        for (int i = 0; i < 4; ++i) {
            gload_lds16(gk + i * 1024, lk + i * 1024);
            gload_lds16(gv + i * 1024, lv + i * 1024);
        }
    };

    // read bases (zero per-read VALU; swizzle folded in)
    const unsigned rsw = (unsigned)(lr & 7) << 4;
    int kbase[4], vbase[2];
#pragma unroll
    for (int kk = 0; kk < 4; ++kk)
        kbase[kk] = lr * 256 + (int)((unsigned)(kk * 64 + g * 16) ^ rsw);
#pragma unroll
    for (int hf = 0; hf < 2; ++hf)
        vbase[hf] = 16384 + lr * 128 + (int)((unsigned)(hf * 64 + g * 16) ^ rsw);

    // Q fragments, 2 q-halves, pre-scaled into exp2 domain
    const int qr0 = qb + 32 * w + lr;
    const float* qbh = q + (size_t)bh * DDIM;
    s16x8 qf[2][4];
#pragma unroll
    for (int qh = 0; qh < 2; ++qh)
#pragma unroll
        for (int kk = 0; kk < 4; ++kk) {
            const float* qp = qbh + (size_t)(qr0 + 16 * qh) * ROWSTR + kk * 32 + g * 8;
            f32x4 a = *(const f32x4*)qp, b = *(const f32x4*)(qp + 4);
            unsigned* tu = (unsigned*)&qf[qh][kk];
            tu[0] = pk2bf(a[0] * QSCALE, a[1] * QSCALE);
            tu[1] = pk2bf(a[2] * QSCALE, a[3] * QSCALE);
            tu[2] = pk2bf(b[0] * QSCALE, b[1] * QSCALE);
            tu[3] = pk2bf(b[2] * QSCALE, b[3] * QSCALE);
        }

    f32x4 acc[8][2];
#pragma unroll
    for (int i = 0; i < 8; ++i) { acc[i][0] = (f32x4){0,0,0,0}; acc[i][1] = (f32x4){0,0,0,0}; }
    float mrun[2] = { -INFINITY, -INFINITY };
    float lrun[2] = { 0.f, 0.f };

    stage_async(0, 0);
    __syncthreads();

    for (int t = 0; t < nt; ++t) {
        const int cur = t & 1;
        if (t + 1 < nt) stage_async(cur ^ 1, t + 1);   // async, drains at barrier

        const char* bK = lds[cur];
        const int kv0 = t * KVBLK;
        const int wqmin = qb + 32 * w;

        if (kv0 <= wqmin + 31) {                       // wave-uniform causal skip
            // ---- S^T = K · Q^T : sa[m][qh], kv = kv0+16m+4g+r, q = qr0+16qh
            f32x4 sa[4][2];
#pragma unroll
            for (int m = 0; m < 4; ++m) { sa[m][0] = (f32x4){0,0,0,0}; sa[m][1] = (f32x4){0,0,0,0}; }
            __builtin_amdgcn_s_setprio(1);
#pragma unroll
            for (int m = 0; m < 4; ++m)
#pragma unroll
                for (int kk = 0; kk < 4; ++kk) {
                    s16x8 kf = *(const s16x8*)(bK + kbase[kk] + m * 4096);
                    sa[m][0] = __builtin_amdgcn_mfma_f32_16x16x32_bf16(kf, qf[0][kk], sa[m][0], 0, 0, 0);
                    sa[m][1] = __builtin_amdgcn_mfma_f32_16x16x32_bf16(kf, qf[1][kk], sa[m][1], 0, 0, 0);
                }
            __builtin_amdgcn_s_setprio(0);

            const bool maskt = (kv0 + KVBLK - 1 > wqmin);
            float mxv[2];
#pragma unroll
            for (int qh = 0; qh < 2; ++qh) {
                int qrow = qr0 + 16 * qh;
                if (maskt) {
#pragma unroll
                    for (int m = 0; m < 4; ++m)
#pragma unroll
                        for (int r = 0; r < 4; ++r)
                            if (kv0 + 16 * m + 4 * g + r > qrow) sa[m][qh][r] = -INFINITY;
                }
                float mx = sa[0][qh][0];
#pragma unroll
                for (int m = 0; m < 4; ++m)
#pragma unroll
                    for (int r = 0; r < 4; ++r) mx = fmaxf(mx, sa[m][qh][r]);
                mx = fmaxf(mx, __shfl_xor(mx, 16));
                mx = fmaxf(mx, __shfl_xor(mx, 32));
                mxv[qh] = mx;
            }

            if (!__all((mxv[0] - mrun[0] <= 8.0f) && (mxv[1] - mrun[1] <= 8.0f))) {
#pragma unroll
                for (int qh = 0; qh < 2; ++qh) {
                    float mnew = fmaxf(mrun[qh], mxv[qh]);
                    float corr = __builtin_amdgcn_exp2f(mrun[qh] - mnew);
                    lrun[qh] *= corr;
#pragma unroll
                    for (int db = 0; db < 8; ++db)
#pragma unroll
                        for (int r = 0; r < 4; ++r) acc[db][qh][r] *= corr;
                    mrun[qh] = mnew;
                }
            }

#pragma unroll
            for (int qh = 0; qh < 2; ++qh) {
                float ts = 0.f;
#pragma unroll
                for (int m = 0; m < 4; ++m)
#pragma unroll
                    for (int r = 0; r < 4; ++r) {
                        float p = __builtin_amdgcn_exp2f(sa[m][qh][r] - mrun[qh]);
                        sa[m][qh][r] = p;
                        ts += p;
                    }
                ts += __shfl_xor(ts, 16);
                ts += __shfl_xor(ts, 32);
                lrun[qh] += ts;
            }

            // ---- pack P: pa[qh][hf][j] <-> kv = kv0+32hf+16(j>>2)+4g+(j&3)
            s16x8 pa[2][2];
#pragma unroll
            for (int qh = 0; qh < 2; ++qh)
#pragma unroll
                for (int hf = 0; hf < 2; ++hf) {
                    unsigned* pu = (unsigned*)&pa[qh][hf];
                    pu[0] = pk2bf(sa[2 * hf][qh][0],     sa[2 * hf][qh][1]);
                    pu[1] = pk2bf(sa[2 * hf][qh][2],     sa[2 * hf][qh][3]);
                    pu[2] = pk2bf(sa[2 * hf + 1][qh][0], sa[2 * hf + 1][qh][1]);
                    pu[3] = pk2bf(sa[2 * hf + 1][qh][2], sa[2 * hf + 1][qh][3]);
                }

            // ---- O^T += V^T · P^T
            __builtin_amdgcn_s_setprio(1);
#pragma unroll
            for (int db = 0; db < 8; ++db)
#pragma unroll
                for (int hf = 0; hf < 2; ++hf) {
                    s16x8 vf = *(const s16x8*)(bK + vbase[hf] + db * 2048);
                    acc[db][0] = __builtin_amdgcn_mfma_f32_16x16x32_bf16(vf, pa[0][hf], acc[db][0], 0, 0, 0);
                    acc[db][1] = __builtin_amdgcn_mfma_f32_16x16x32_bf16(vf, pa[1][hf], acc[db][1], 0, 0, 0);
                }
            __builtin_amdgcn_s_setprio(0);
        }
        __syncthreads();
    }

    // ---- epilogue: lane holds O[qr0+16qh][d = db*16 + 4g + r]
#pragma unroll
    for (int qh = 0; qh < 2; ++qh) {
        float inv = 1.0f / lrun[qh];
        float* op = out + (size_t)(qr0 + 16 * qh) * ROWSTR + bh * DDIM;
#pragma unroll
        for (int db = 0; db < 8; ++db) {
            f32x4 o;
#pragma unroll
            for (int r = 0; r < 4; ++r) o[r] = acc[db][qh][r] * inv;
            *(f32x4*)(op + db * 16 + g * 4) = o;
        }
    }
}

extern "C" void kernel_launch(void* const* d_in, const int* in_sizes, int n_in,
                              void* d_out, int out_size, void* d_ws, size_t ws_size,
                              hipStream_t stream) {
    const float* q = (const float*)d_in[0];
    const float* k = (const float*)d_in[1];
    const float* v = (const float*)d_in[2];
    float* o = (float*)d_out;
    char* ws = (char*)d_ws;
    prep_kernel<<<dim3(2048), dim3(256), 0, stream>>>(k, v, ws);
    fattn_kernel<<<dim3(512), dim3(256), 0, stream>>>(q, ws, o);
}